// Round 17
// baseline (861.016 us; speedup 1.0000x reference)
//
#include <hip/hip_runtime.h>
#include <hip/hip_bf16.h>

// TransformerBlock: N=4, T=2048, D=1024. bf16 MFMA 16x16x32, NT GEMMs.
// R17 = R16 base + "gemmD" for QKV: 256x256 tile, BK=32, TWO 32KB LDS buffers
// (64KB -> 2 blocks/CU), minimum-2-phase schedule (stage(t+1); reads(t);
// lgkm0; MFMA; vmcnt0; barrier), wave tile 128x64 (2.67 MFMA/ds_read ->
// MFMA-bound per-CU). scores: gemmT4; ctx/MLP: gemmT8 (R16 proven).

typedef __attribute__((ext_vector_type(8))) short short8;
typedef __attribute__((ext_vector_type(4))) short short4v;
typedef __attribute__((ext_vector_type(4))) float float4v;

#define DEVI static __device__ __forceinline__

DEVI float bf2f(short s) {
  union { unsigned u; float f; } c;
  c.u = ((unsigned)(unsigned short)s) << 16;
  return c.f;
}
DEVI short f2bf(float f) {
  union { __hip_bfloat16 h; short s; } c;
  c.h = __float2bfloat16(f);
  return c.s;
}
DEVI void gload_lds16(const void* g, void* l) {
  __builtin_amdgcn_global_load_lds(
      (const __attribute__((address_space(1))) void*)g,
      (__attribute__((address_space(3))) void*)l, 16, 0, 0);
}

#define MFMA16 __builtin_amdgcn_mfma_f32_16x16x32_bf16
#define CFENCE asm volatile("" ::: "memory")
#define SCHEDB __builtin_amdgcn_sched_barrier(0)

// ---------------- gemmD: 256x256, 2x32KB double-buffer, 2 blocks/CU (QKV) ----
// flags: 1=bias, 2=relu, 4=fp32 output, 8=QKV split (cols>=2048 -> vTo transposed)
__global__ __launch_bounds__(512, 4) void gemmD(
    const short* __restrict__ A, const short* __restrict__ B,
    const float* __restrict__ bias, float alpha, void* __restrict__ Cout,
    int K, int lda, int ldb, int ldc,
    long sA, long sB, long sC, int flags, short* __restrict__ vTo)
{
  constexpr int BUFB = 32768;
  __shared__ __attribute__((aligned(16))) char lds[2 * BUFB];

  const int tid  = threadIdx.x;
  const int lane = tid & 63;
  const int wid  = tid >> 6;
  const int wm = wid >> 2, wn = wid & 3;   // 2(M) x 4(N); wave tile 128x64
  const int lr = lane & 15;
  const int kq = lane >> 4;

  const long m0 = (long)blockIdx.x * 256;
  const long n0 = (long)blockIdx.y * 256;
  const short* Ab = A + (long)blockIdx.z * sA;
  const short* Bb = B + (long)blockIdx.z * sB;

  // staging: dest slot = row*4 + c' (16B chunks); src chunk = c' ^ ((row>>1)&3).
  const int sc8 = (((tid & 3) ^ ((tid >> 3) & 3)) << 3);
  const short* pA0 = Ab + (m0 + (tid >> 2)) * (long)lda + sc8;        // rows 0..127
  const short* pA1 = Ab + (m0 + 128 + (tid >> 2)) * (long)lda + sc8;  // rows 128..255
  const short* pB0 = Bb + (n0 + (tid >> 2)) * (long)ldb + sc8;        // rows 0..127
  const short* pB1 = Bb + (n0 + 128 + (tid >> 2)) * (long)ldb + sc8;  // rows 128..255

  char* ldsB = lds;
  const int dst0 = tid * 16;

  auto stage = [&](int bs, int kt) {     // 4 loads / thread
    const long ko = (long)kt * 32;
    gload_lds16(pA0 + ko, ldsB + bs + dst0);
    gload_lds16(pA1 + ko, ldsB + bs + 8192 + dst0);
    gload_lds16(pB0 + ko, ldsB + bs + 16384 + dst0);
    gload_lds16(pB1 + ko, ldsB + bs + 24576 + dst0);
  };

  const int swz = ((kq ^ ((lr >> 1) & 3)) << 4);
  const int baseA = (wm * 128 + lr) * 64 + swz;
  const int baseB = 16384 + (wn * 64 + lr) * 64 + swz;

  float4v acc[8][4];
#pragma unroll
  for (int m = 0; m < 8; ++m)
#pragma unroll
    for (int n = 0; n < 4; ++n)
#pragma unroll
      for (int i = 0; i < 4; ++i) acc[m][n][i] = 0.f;

  const int NT = K >> 5;

  // prologue: stage tile0; drain; barrier.
  stage(0, 0);
  asm volatile("s_waitcnt vmcnt(0)" ::: "memory");
  __builtin_amdgcn_s_barrier();
  CFENCE;

  for (int t = 0; t < NT; ++t) {
    const int bsR = (t & 1) * BUFB;
    if (t + 1 < NT) stage(((t + 1) & 1) * BUFB, t + 1);

    const char* rA = ldsB + (bsR + baseA);
    const char* rB = ldsB + (bsR + baseB);
    short8 af[8], bf[4];
#pragma unroll
    for (int m = 0; m < 8; ++m) af[m] = *(const short8*)(rA + m * 1024);
#pragma unroll
    for (int n = 0; n < 4; ++n) bf[n] = *(const short8*)(rB + n * 1024);

    asm volatile("s_waitcnt lgkmcnt(0)" ::: "memory");
    SCHEDB;
    __builtin_amdgcn_s_setprio(1);
#pragma unroll
    for (int m = 0; m < 8; ++m)
#pragma unroll
      for (int n = 0; n < 4; ++n)
        acc[m][n] = MFMA16(af[m], bf[n], acc[m][n], 0, 0, 0);
    __builtin_amdgcn_s_setprio(0);

    asm volatile("s_waitcnt vmcnt(0)" ::: "memory");
    __builtin_amdgcn_s_barrier();
    CFENCE;
  }

  // ---- epilogue ----
  const int dob = flags & 1, dor = flags & 2, f32o = flags & 4;
  float* Cf = (float*)Cout + (long)blockIdx.z * sC;
  short* Cb = (short*)Cout + (long)blockIdx.z * sC;
  const long r0 = m0 + wm * 128 + kq * 4;
  const long c0 = n0 + wn * 64 + lr;
#pragma unroll
  for (int m = 0; m < 8; ++m)
#pragma unroll
    for (int n = 0; n < 4; ++n) {
      const long c = c0 + n * 16;
      float bv = dob ? bias[c] : 0.f;
      const bool vside = (flags & 8) && (c >= 2048);
      if (vside) {
        const long rb = r0 + m * 16;
        short4v pv;
#pragma unroll
        for (int i = 0; i < 4; ++i) pv[i] = f2bf(acc[m][n][i] * alpha + bv);
        const long vr = ((rb >> 11) << 21) + ((c - 2048) << 11) + (rb & 2047);
        *(short4v*)&vTo[vr] = pv;
      } else {
#pragma unroll
        for (int i = 0; i < 4; ++i) {
          const long r = r0 + m * 16 + i;
          float v = acc[m][n][i] * alpha + bv;
          if (dor) v = fmaxf(v, 0.f);
          if (f32o) Cf[r * ldc + c] = v;
          else      Cb[r * ldc + c] = f2bf(v);
        }
      }
    }
}

// ---------------- gemmT4: 256x128, 2 blocks/CU (scores) ----------------
__global__ __launch_bounds__(512, 4) void gemmT4(
    const short* __restrict__ A, const short* __restrict__ B,
    const float* __restrict__ bias, float alpha, void* __restrict__ Cout,
    int K, int lda, int ldb, int ldc,
    long sA, long sB, long sC, int flags, short* __restrict__ vTo)
{
  constexpr int BUFB = 24576;
  __shared__ __attribute__((aligned(16))) char lds[3 * BUFB];

  const int tid  = threadIdx.x;
  const int lane = tid & 63;
  const int wid  = tid >> 6;
  const int wm = wid >> 1, wn = wid & 1;   // 4(M) x 2(N); wave tile 64x64
  const int lr = lane & 15;
  const int kq = lane >> 4;

  const long m0 = (long)blockIdx.x * 256;
  const long n0 = (long)blockIdx.y * 128;
  const short* Ab = A + (long)blockIdx.z * sA;
  const short* Bb = B + (long)blockIdx.z * sB;

  const int sc8 = (((tid & 3) ^ ((tid >> 3) & 3)) << 3);
  const short* pA0 = Ab + (m0 + (tid >> 2)) * (long)lda + sc8;
  const short* pA1 = Ab + (m0 + 128 + (tid >> 2)) * (long)lda + sc8;
  const short* pB  = Bb + (n0 + (tid >> 2)) * (long)ldb + sc8;

  char* ldsB = lds;
  const int dst0 = tid * 16;

  auto stage = [&](int bs, int kt) {
    const long ko = (long)kt * 32;
    gload_lds16(pA0 + ko, ldsB + bs + dst0);
    gload_lds16(pA1 + ko, ldsB + bs + 8192 + dst0);
    gload_lds16(pB  + ko, ldsB + bs + 16384 + dst0);
  };

  const int swz = ((kq ^ ((lr >> 1) & 3)) << 4);
  const int baseA = (wm * 64 + lr) * 64 + swz;
  const int baseB = 16384 + (wn * 64 + lr) * 64 + swz;

  float4v acc[4][4];
#pragma unroll
  for (int m = 0; m < 4; ++m)
#pragma unroll
    for (int n = 0; n < 4; ++n)
#pragma unroll
      for (int i = 0; i < 4; ++i) acc[m][n][i] = 0.f;

  const int NT = K >> 5;

  stage(0, 0);
  stage(BUFB, 1);
  asm volatile("s_waitcnt vmcnt(3)" ::: "memory");
  __builtin_amdgcn_s_barrier();
  CFENCE;

  int bsR = 0;
  int bsS = 2 * BUFB;

  for (int t = 0; t < NT; ++t) {
    if (t + 2 < NT) stage(bsS, t + 2);

    const char* rA = ldsB + (bsR + baseA);
    const char* rB = ldsB + (bsR + baseB);
    short8 a0 = *(const short8*)(rA);
    short8 a1 = *(const short8*)(rA + 1024);
    short8 a2 = *(const short8*)(rA + 2048);
    short8 a3 = *(const short8*)(rA + 3072);
    short8 b0 = *(const short8*)(rB);
    short8 b1 = *(const short8*)(rB + 1024);
    short8 b2 = *(const short8*)(rB + 2048);
    short8 b3 = *(const short8*)(rB + 3072);

    asm volatile("s_waitcnt lgkmcnt(0)" ::: "memory");
    SCHEDB;
    __builtin_amdgcn_s_setprio(1);
    acc[0][0] = MFMA16(a0, b0, acc[0][0], 0, 0, 0);
    acc[0][1] = MFMA16(a0, b1, acc[0][1], 0, 0, 0);
    acc[0][2] = MFMA16(a0, b2, acc[0][2], 0, 0, 0);
    acc[0][3] = MFMA16(a0, b3, acc[0][3], 0, 0, 0);
    acc[1][0] = MFMA16(a1, b0, acc[1][0], 0, 0, 0);
    acc[1][1] = MFMA16(a1, b1, acc[1][1], 0, 0, 0);
    acc[1][2] = MFMA16(a1, b2, acc[1][2], 0, 0, 0);
    acc[1][3] = MFMA16(a1, b3, acc[1][3], 0, 0, 0);
    acc[2][0] = MFMA16(a2, b0, acc[2][0], 0, 0, 0);
    acc[2][1] = MFMA16(a2, b1, acc[2][1], 0, 0, 0);
    acc[2][2] = MFMA16(a2, b2, acc[2][2], 0, 0, 0);
    acc[2][3] = MFMA16(a2, b3, acc[2][3], 0, 0, 0);
    acc[3][0] = MFMA16(a3, b0, acc[3][0], 0, 0, 0);
    acc[3][1] = MFMA16(a3, b1, acc[3][1], 0, 0, 0);
    acc[3][2] = MFMA16(a3, b2, acc[3][2], 0, 0, 0);
    acc[3][3] = MFMA16(a3, b3, acc[3][3], 0, 0, 0);
    __builtin_amdgcn_s_setprio(0);

    if (t + 2 < NT) { asm volatile("s_waitcnt vmcnt(3)" ::: "memory"); }
    else            { asm volatile("s_waitcnt vmcnt(0)" ::: "memory"); }
    __builtin_amdgcn_s_barrier();
    CFENCE;

    bsR = (bsR == 2 * BUFB) ? 0 : bsR + BUFB;
    bsS = (bsS == 2 * BUFB) ? 0 : bsS + BUFB;
  }

  const int dob = flags & 1, dor = flags & 2, f32o = flags & 4;
  const bool vside = (flags & 8) && (n0 >= 2048);
  float* Cf = (float*)Cout + (long)blockIdx.z * sC;
  short* Cb = (short*)Cout + (long)blockIdx.z * sC;
  const long r0 = m0 + wm * 64 + kq * 4;
  const long c0 = n0 + wn * 64 + lr;
#pragma unroll
  for (int m = 0; m < 4; ++m)
#pragma unroll
    for (int n = 0; n < 4; ++n) {
      const long c = c0 + n * 16;
      float bv = dob ? bias[c] : 0.f;
      if (vside) {
        const long rb = r0 + m * 16;
        short4v pv;
#pragma unroll
        for (int i = 0; i < 4; ++i) pv[i] = f2bf(acc[m][n][i] * alpha + bv);
        const long vr = ((rb >> 11) << 21) + ((c - 2048) << 11) + (rb & 2047);
        *(short4v*)&vTo[vr] = pv;
      } else {
#pragma unroll
        for (int i = 0; i < 4; ++i) {
          const long r = r0 + m * 16 + i;
          float v = acc[m][n][i] * alpha + bv;
          if (dor) v = fmaxf(v, 0.f);
          if (f32o) Cf[r * ldc + c] = v;
          else      Cb[r * ldc + c] = f2bf(v);
        }
      }
    }
}

// ---------------- gemmT8: 128x128, 3 blocks/CU (ctx, MLP) ----------------
__global__ __launch_bounds__(512, 6) void gemmT8(
    const short* __restrict__ A, const short* __restrict__ B,
    const float* __restrict__ bias, float alpha, void* __restrict__ Cout,
    int K, int lda, int ldb, int ldc,
    long sA, long sB, long sC, int flags)
{
  constexpr int BUFB = 16384;
  __shared__ __attribute__((aligned(16))) char lds[3 * BUFB];

  const int tid  = threadIdx.x;
  const int lane = tid & 63;
  const int wid  = tid >> 6;
  const int wm = wid >> 2, wn = wid & 3;   // 2(M) x 4(N); wave tile 64x32
  const int lr = lane & 15;
  const int kq = lane >> 4;

  const long m0 = (long)blockIdx.x * 128;
  const long n0 = (long)blockIdx.y * 128;
  const short* Ab = A + (long)blockIdx.z * sA;
  const short* Bb = B + (long)blockIdx.z * sB;

  const int sc8 = (((tid & 3) ^ ((tid >> 3) & 3)) << 3);
  const short* pA = Ab + (m0 + (tid >> 2)) * (long)lda + sc8;
  const short* pB = Bb + (n0 + (tid >> 2)) * (long)ldb + sc8;

  char* ldsB = lds;
  const int dst0 = tid * 16;

  auto stage = [&](int bs, int kt) {
    const long ko = (long)kt * 32;
    gload_lds16(pA + ko, ldsB + bs + dst0);
    gload_lds16(pB + ko, ldsB + bs + 8192 + dst0);
  };

  const int swz = ((kq ^ ((lr >> 1) & 3)) << 4);
  const int baseA = (wm * 64 + lr) * 64 + swz;
  const int baseB = 8192 + (wn * 32 + lr) * 64 + swz;

  float4v acc[4][2];
#pragma unroll
  for (int m = 0; m < 4; ++m)
#pragma unroll
    for (int n = 0; n < 2; ++n)
#pragma unroll
      for (int i = 0; i < 4; ++i) acc[m][n][i] = 0.f;

  const int NT = K >> 5;

  stage(0, 0);
  stage(BUFB, 1);
  asm volatile("s_waitcnt vmcnt(2)" ::: "memory");
  __builtin_amdgcn_s_barrier();
  CFENCE;

  int bsR = 0;
  int bsS = 2 * BUFB;

  for (int t = 0; t < NT; ++t) {
    if (t + 2 < NT) stage(bsS, t + 2);

    const char* rA = ldsB + (bsR + baseA);
    const char* rB = ldsB + (bsR + baseB);
    short8 a0 = *(const short8*)(rA);
    short8 a1 = *(const short8*)(rA + 1024);
    short8 a2 = *(const short8*)(rA + 2048);
    short8 a3 = *(const short8*)(rA + 3072);
    short8 b0 = *(const short8*)(rB);
    short8 b1 = *(const short8*)(rB + 1024);

    asm volatile("s_waitcnt lgkmcnt(0)" ::: "memory");
    SCHEDB;
    __builtin_amdgcn_s_setprio(1);
    acc[0][0] = MFMA16(a0, b0, acc[0][0], 0, 0, 0);
    acc[0][1] = MFMA16(a0, b1, acc[0][1], 0, 0, 0);
    acc[1][0] = MFMA16(a1, b0, acc[1][0], 0, 0, 0);
    acc[1][1] = MFMA16(a1, b1, acc[1][1], 0, 0, 0);
    acc[2][0] = MFMA16(a2, b0, acc[2][0], 0, 0, 0);
    acc[2][1] = MFMA16(a2, b1, acc[2][1], 0, 0, 0);
    acc[3][0] = MFMA16(a3, b0, acc[3][0], 0, 0, 0);
    acc[3][1] = MFMA16(a3, b1, acc[3][1], 0, 0, 0);
    __builtin_amdgcn_s_setprio(0);

    if (t + 2 < NT) { asm volatile("s_waitcnt vmcnt(2)" ::: "memory"); }
    else            { asm volatile("s_waitcnt vmcnt(0)" ::: "memory"); }
    __builtin_amdgcn_s_barrier();
    CFENCE;

    bsR = (bsR == 2 * BUFB) ? 0 : bsR + BUFB;
    bsS = (bsS == 2 * BUFB) ? 0 : bsS + BUFB;
  }

  const int dob = flags & 1, dor = flags & 2, f32o = flags & 4;
  float* Cf = (float*)Cout + (long)blockIdx.z * sC;
  short* Cb = (short*)Cout + (long)blockIdx.z * sC;
  const long r0 = m0 + wm * 64 + kq * 4;
  const long c0 = n0 + wn * 32 + lr;
#pragma unroll
  for (int m = 0; m < 4; ++m)
#pragma unroll
    for (int n = 0; n < 2; ++n) {
      const long c = c0 + n * 16;
      float bv = dob ? bias[c] : 0.f;
#pragma unroll
      for (int i = 0; i < 4; ++i) {
        const long r = r0 + m * 16 + i;
        float v = acc[m][n][i] * alpha + bv;
        if (dor) v = fmaxf(v, 0.f);
        if (f32o) Cf[r * ldc + c] = v;
        else      Cb[r * ldc + c] = f2bf(v);
      }
    }
}

// ---------------- elementwise / utility kernels ----------------

__global__ __launch_bounds__(256) void cast_x_k(const float* __restrict__ X,
                                                short* __restrict__ Xb) {
  int i = blockIdx.x * 256 + threadIdx.x;
  float4v v = ((const float4v*)X)[i];
  short4v o;
#pragma unroll
  for (int j = 0; j < 4; ++j) o[j] = f2bf(v[j]);
  ((short4v*)Xb)[i] = o;
}

__global__ __launch_bounds__(256) void wcast_k(
    const float* __restrict__ Wq, const float* __restrict__ Wk,
    const float* __restrict__ Wv, const float* __restrict__ W1,
    const float* __restrict__ W2, const float* __restrict__ W3,
    const float* __restrict__ bq, const float* __restrict__ bk,
    const float* __restrict__ bv,
    short* __restrict__ Wqkvt, short* __restrict__ W1t,
    short* __restrict__ W2t, short* __restrict__ W3t,
    float* __restrict__ bqkv) {
  const int z = blockIdx.z;
  if (z == 6) {
    if (blockIdx.y != 0 || blockIdx.x >= 12) return;
    int i = blockIdx.x * 256 + threadIdx.x;
    bqkv[i] = i < 1024 ? bq[i] : (i < 2048 ? bk[i - 1024] : bv[i - 2048]);
    return;
  }
  const float* W = z == 0 ? Wq : z == 1 ? Wk : z == 2 ? Wv : z == 3 ? W1 : z == 4 ? W2 : W3;
  short* Wt = z == 0 ? Wqkvt : z == 1 ? Wqkvt + 1048576 : z == 2 ? Wqkvt + 2097152
            : z == 3 ? W1t : z == 4 ? W2t : W3t;
  __shared__ float tile[32][33];
  int tx = threadIdx.x & 31, ty = threadIdx.x >> 5;
  int c0 = blockIdx.x * 32, r0 = blockIdx.y * 32;
#pragma unroll
  for (int r = ty; r < 32; r += 8)
    tile[r][tx] = W[(long)(r0 + r) * 1024 + c0 + tx];
  __syncthreads();
#pragma unroll
  for (int r = ty; r < 32; r += 8)
    Wt[(long)(c0 + r) * 1024 + r0 + tx] = f2bf(tile[tx][r]);
}

__global__ __launch_bounds__(256) void softmax_k(short* __restrict__ s) {
  __shared__ float red[8];
  long r = blockIdx.x;
  short* p = s + r * 2048;
  int tid = threadIdx.x;
  short8 raw = *(short8*)&p[tid * 8];
  float v[8];
  float mx = -1e30f;
#pragma unroll
  for (int j = 0; j < 8; ++j) { v[j] = bf2f(raw[j]); mx = fmaxf(mx, v[j]); }
#pragma unroll
  for (int o = 32; o; o >>= 1) mx = fmaxf(mx, __shfl_xor(mx, o));
  if ((tid & 63) == 0) red[tid >> 6] = mx;
  __syncthreads();
  mx = fmaxf(fmaxf(red[0], red[1]), fmaxf(red[2], red[3]));
  float sum = 0.f;
#pragma unroll
  for (int j = 0; j < 8; ++j) { v[j] = __expf(v[j] - mx); sum += v[j]; }
#pragma unroll
  for (int o = 32; o; o >>= 1) sum += __shfl_xor(sum, o);
  if ((tid & 63) == 0) red[4 + (tid >> 6)] = sum;
  __syncthreads();
  float inv = 1.f / (red[4] + red[5] + red[6] + red[7]);
  short8 o8;
#pragma unroll
  for (int j = 0; j < 8; ++j) o8[j] = f2bf(v[j] * inv);
  *(short8*)&p[tid * 8] = o8;
}

// LN(a_bf + b_bf): outf fp32 (optional), outb bf16 (optional)
__global__ __launch_bounds__(256) void addln2_k(const short* __restrict__ a,
                                                const short* __restrict__ b,
                                                const float* __restrict__ g,
                                                const float* __restrict__ be,
                                                float* __restrict__ outf,
                                                short* __restrict__ outb) {
  __shared__ float red[8];
  long r = blockIdx.x;
  int tid = threadIdx.x;
  short4v va = ((const short4v*)(a + r * 1024))[tid];
  short4v vb = ((const short4v*)(b + r * 1024))[tid];
  float x[4]; float s = 0.f;
#pragma unroll
  for (int j = 0; j < 4; ++j) { x[j] = bf2f(va[j]) + bf2f(vb[j]); s += x[j]; }
#pragma unroll
  for (int o = 32; o; o >>= 1) s += __shfl_xor(s, o);
  if ((tid & 63) == 0) red[tid >> 6] = s;
  __syncthreads();
  float mu = (red[0] + red[1] + red[2] + red[3]) * (1.f / 1024.f);
  float ss = 0.f;
#pragma unroll
  for (int j = 0; j < 4; ++j) { float d = x[j] - mu; ss += d * d; }
#pragma unroll
  for (int o = 32; o; o >>= 1) ss += __shfl_xor(ss, o);
  if ((tid & 63) == 0) red[4 + (tid >> 6)] = ss;
  __syncthreads();
  float var = (red[4] + red[5] + red[6] + red[7]) * (1.f / 1024.f);
  float rstd = rsqrtf(var + 1e-5f);
  float4v vg = ((const float4v*)g)[tid];
  float4v vbe = ((const float4v*)be)[tid];
  float4v y;
#pragma unroll
  for (int j = 0; j < 4; ++j) y[j] = (x[j] - mu) * rstd * vg[j] + vbe[j];
  if (outf) ((float4v*)(outf + r * 1024))[tid] = y;
  if (outb) {
    short4v ob;
#pragma unroll
    for (int j = 0; j < 4; ++j) ob[j] = f2bf(y[j]);
    ((short4v*)(outb + r * 1024))[tid] = ob;
  }
}

// ---------------- host launcher ----------------

extern "C" void kernel_launch(void* const* d_in, const int* in_sizes, int n_in,
                              void* d_out, int out_size, void* d_ws, size_t ws_size,
                              hipStream_t stream) {
  const float* X  = (const float*)d_in[0];
  const float* Wq = (const float*)d_in[1];
  const float* bq = (const float*)d_in[2];
  const float* Wk = (const float*)d_in[3];
  const float* bk = (const float*)d_in[4];
  const float* Wv = (const float*)d_in[5];
  const float* bv = (const float*)d_in[6];
  const float* W1 = (const float*)d_in[7];
  const float* b1 = (const float*)d_in[8];
  const float* W2 = (const float*)d_in[9];
  const float* b2 = (const float*)d_in[10];
  const float* W3 = (const float*)d_in[11];
  const float* b3 = (const float*)d_in[12];
  const float* g1  = (const float*)d_in[13];
  const float* be1 = (const float*)d_in[14];
  const float* g2  = (const float*)d_in[15];
  const float* be2 = (const float*)d_in[16];

  char* ws = (char*)d_ws;
  short* Xb     = (short*)(ws + 0);           // 16.7 MB, live to LN1
  short* Wqkvt  = (short*)(ws + 16777216);
  short* W1t    = (short*)(ws + 23068672);
  short* W2t    = (short*)(ws + 25165824);
  short* W3t    = (short*)(ws + 27262976);
  float* bqkv   = (float*)(ws + 29360128);
  short* qk     = (short*)(ws + 29372416);    // [8192][2048] bf16 = 33.5 MB
  short* vT     = (short*)(ws + 62926848);    // [4][1024][2048] bf16 = 16.7 MB
  short* scores = (short*)(ws + 79704064);    // 33.5 MB
  short* ctx    = (short*)(ws + 29372416);    // over qk lower half
  short* hbuf   = (short*)(ws + 46149632);    // over qk upper half
  short* m1     = (short*)(ws + 62926848);    // over vT (dead after ctx)
  short* m2     = (short*)(ws + 79704064);    // over scores (dead after ctx)
  short* m3     = (short*)(ws + 96481280);
  float* out    = (float*)d_out;

  cast_x_k<<<8192, 256, 0, stream>>>(X, Xb);
  wcast_k<<<dim3(32, 32, 7), 256, 0, stream>>>(Wq, Wk, Wv, W1, W2, W3,
                                               bq, bk, bv,
                                               Wqkvt, W1t, W2t, W3t, bqkv);

  // QKV: gemmD 256x256; grid 32x12 = 384 blocks
  gemmD<<<dim3(32, 12, 1), 512, 0, stream>>>(
      Xb, Wqkvt, bqkv, 1.0f, qk, 1024, 1024, 1024, 2048, 0, 0, 0, 1 | 8, vT);

  // scores[b] = q k^T / 32; gemmT4 grid 8x16x4 (512 blocks, 2/CU)
  gemmT4<<<dim3(8, 16, 4), 512, 0, stream>>>(
      qk, qk + 1024, nullptr, 0.03125f, scores, 1024, 2048, 2048, 2048,
      (long)2048 * 2048, (long)2048 * 2048, (long)2048 * 2048, 0, nullptr);

  softmax_k<<<8192, 256, 0, stream>>>(scores);

  // ctx[b] = attn @ v (bf16); gemmT8 grid 16x8x4 = 512 blocks
  gemmT8<<<dim3(16, 8, 4), 512, 0, stream>>>(
      scores, vT, nullptr, 1.0f, ctx, 2048, 2048, 2048, 1024,
      (long)2048 * 2048, (long)1024 * 2048, (long)2048 * 1024, 0);

  // h = LN(ctx + Xb), bf16 only
  addln2_k<<<8192, 256, 0, stream>>>(ctx, Xb, g1, be1, nullptr, hbuf);

  // MLP: gemmT8 grid 64x8 = 512 blocks each; bf16 outputs
  gemmT8<<<dim3(64, 8, 1), 512, 0, stream>>>(
      hbuf, W1t, b1, 1.0f, m1, 1024, 1024, 1024, 1024, 0, 0, 0, 3);
  gemmT8<<<dim3(64, 8, 1), 512, 0, stream>>>(
      m1, W2t, b2, 1.0f, m2, 1024, 1024, 1024, 1024, 0, 0, 0, 3);
  gemmT8<<<dim3(64, 8, 1), 512, 0, stream>>>(
      m2, W3t, b3, 1.0f, m3, 1024, 1024, 1024, 1024, 0, 0, 0, 1);

  // out = LN(m3 + h), fp32
  addln2_k<<<8192, 256, 0, stream>>>(m3, hbuf, g2, be2, out, nullptr);
}

// Round 18
// 282.039 us; speedup vs baseline: 3.0528x; 3.0528x over previous
//
#include <hip/hip_runtime.h>
#include <hip/hip_bf16.h>

// TransformerBlock: N=4, T=2048, D=1024. bf16 MFMA 16x16x32, NT GEMMs.
// R18 = exact revert to R16 (best measured: 283.0 us). Lesson from R17: a
// 512-thread block needs <=128 VGPR/wave for 2 blocks/CU; acc[8][4] (256^2
// tile) spills -> 256x128 (gemmT4, acc 64+56=120) is the occupancy sweet spot.

typedef __attribute__((ext_vector_type(8))) short short8;
typedef __attribute__((ext_vector_type(4))) short short4v;
typedef __attribute__((ext_vector_type(4))) float float4v;

#define DEVI static __device__ __forceinline__

DEVI float bf2f(short s) {
  union { unsigned u; float f; } c;
  c.u = ((unsigned)(unsigned short)s) << 16;
  return c.f;
}
DEVI short f2bf(float f) {
  union { __hip_bfloat16 h; short s; } c;
  c.h = __float2bfloat16(f);
  return c.s;
}
DEVI void gload_lds16(const void* g, void* l) {
  __builtin_amdgcn_global_load_lds(
      (const __attribute__((address_space(1))) void*)g,
      (__attribute__((address_space(3))) void*)l, 16, 0, 0);
}

#define MFMA16 __builtin_amdgcn_mfma_f32_16x16x32_bf16
#define CFENCE asm volatile("" ::: "memory")
#define SCHEDB __builtin_amdgcn_sched_barrier(0)

// ---------------- gemmT4: 256x128, 2 blocks/CU (QKV, scores) ----------------
// flags: 1=bias, 2=relu, 4=fp32 output, 8=QKV split (cols>=2048 -> vTo transposed)
__global__ __launch_bounds__(512, 4) void gemmT4(
    const short* __restrict__ A, const short* __restrict__ B,
    const float* __restrict__ bias, float alpha, void* __restrict__ Cout,
    int K, int lda, int ldb, int ldc,
    long sA, long sB, long sC, int flags, short* __restrict__ vTo)
{
  constexpr int BUFB = 24576;
  __shared__ __attribute__((aligned(16))) char lds[3 * BUFB];

  const int tid  = threadIdx.x;
  const int lane = tid & 63;
  const int wid  = tid >> 6;
  const int wm = wid >> 1, wn = wid & 1;   // 4(M) x 2(N); wave tile 64x64
  const int lr = lane & 15;
  const int kq = lane >> 4;

  const long m0 = (long)blockIdx.x * 256;
  const long n0 = (long)blockIdx.y * 128;
  const short* Ab = A + (long)blockIdx.z * sA;
  const short* Bb = B + (long)blockIdx.z * sB;

  const int sc8 = (((tid & 3) ^ ((tid >> 3) & 3)) << 3);
  const short* pA0 = Ab + (m0 + (tid >> 2)) * (long)lda + sc8;
  const short* pA1 = Ab + (m0 + 128 + (tid >> 2)) * (long)lda + sc8;
  const short* pB  = Bb + (n0 + (tid >> 2)) * (long)ldb + sc8;

  char* ldsB = lds;
  const int dst0 = tid * 16;

  auto stage = [&](int bs, int kt) {     // 3 loads / thread
    const long ko = (long)kt * 32;
    gload_lds16(pA0 + ko, ldsB + bs + dst0);
    gload_lds16(pA1 + ko, ldsB + bs + 8192 + dst0);
    gload_lds16(pB  + ko, ldsB + bs + 16384 + dst0);
  };

  const int swz = ((kq ^ ((lr >> 1) & 3)) << 4);
  const int baseA = (wm * 64 + lr) * 64 + swz;
  const int baseB = 16384 + (wn * 64 + lr) * 64 + swz;

  float4v acc[4][4];
#pragma unroll
  for (int m = 0; m < 4; ++m)
#pragma unroll
    for (int n = 0; n < 4; ++n)
#pragma unroll
      for (int i = 0; i < 4; ++i) acc[m][n][i] = 0.f;

  const int NT = K >> 5;

  stage(0, 0);
  stage(BUFB, 1);
  asm volatile("s_waitcnt vmcnt(3)" ::: "memory");
  __builtin_amdgcn_s_barrier();
  CFENCE;

  int bsR = 0;
  int bsS = 2 * BUFB;

  for (int t = 0; t < NT; ++t) {
    if (t + 2 < NT) stage(bsS, t + 2);

    const char* rA = ldsB + (bsR + baseA);
    const char* rB = ldsB + (bsR + baseB);
    short8 a0 = *(const short8*)(rA);
    short8 a1 = *(const short8*)(rA + 1024);
    short8 a2 = *(const short8*)(rA + 2048);
    short8 a3 = *(const short8*)(rA + 3072);
    short8 b0 = *(const short8*)(rB);
    short8 b1 = *(const short8*)(rB + 1024);
    short8 b2 = *(const short8*)(rB + 2048);
    short8 b3 = *(const short8*)(rB + 3072);

    asm volatile("s_waitcnt lgkmcnt(0)" ::: "memory");
    SCHEDB;
    __builtin_amdgcn_s_setprio(1);
    acc[0][0] = MFMA16(a0, b0, acc[0][0], 0, 0, 0);
    acc[0][1] = MFMA16(a0, b1, acc[0][1], 0, 0, 0);
    acc[0][2] = MFMA16(a0, b2, acc[0][2], 0, 0, 0);
    acc[0][3] = MFMA16(a0, b3, acc[0][3], 0, 0, 0);
    acc[1][0] = MFMA16(a1, b0, acc[1][0], 0, 0, 0);
    acc[1][1] = MFMA16(a1, b1, acc[1][1], 0, 0, 0);
    acc[1][2] = MFMA16(a1, b2, acc[1][2], 0, 0, 0);
    acc[1][3] = MFMA16(a1, b3, acc[1][3], 0, 0, 0);
    acc[2][0] = MFMA16(a2, b0, acc[2][0], 0, 0, 0);
    acc[2][1] = MFMA16(a2, b1, acc[2][1], 0, 0, 0);
    acc[2][2] = MFMA16(a2, b2, acc[2][2], 0, 0, 0);
    acc[2][3] = MFMA16(a2, b3, acc[2][3], 0, 0, 0);
    acc[3][0] = MFMA16(a3, b0, acc[3][0], 0, 0, 0);
    acc[3][1] = MFMA16(a3, b1, acc[3][1], 0, 0, 0);
    acc[3][2] = MFMA16(a3, b2, acc[3][2], 0, 0, 0);
    acc[3][3] = MFMA16(a3, b3, acc[3][3], 0, 0, 0);
    __builtin_amdgcn_s_setprio(0);

    if (t + 2 < NT) { asm volatile("s_waitcnt vmcnt(3)" ::: "memory"); }
    else            { asm volatile("s_waitcnt vmcnt(0)" ::: "memory"); }
    __builtin_amdgcn_s_barrier();
    CFENCE;

    bsR = (bsR == 2 * BUFB) ? 0 : bsR + BUFB;
    bsS = (bsS == 2 * BUFB) ? 0 : bsS + BUFB;
  }

  const int dob = flags & 1, dor = flags & 2, f32o = flags & 4;
  const bool vside = (flags & 8) && (n0 >= 2048);
  float* Cf = (float*)Cout + (long)blockIdx.z * sC;
  short* Cb = (short*)Cout + (long)blockIdx.z * sC;
  const long r0 = m0 + wm * 64 + kq * 4;
  const long c0 = n0 + wn * 64 + lr;
#pragma unroll
  for (int m = 0; m < 4; ++m)
#pragma unroll
    for (int n = 0; n < 4; ++n) {
      const long c = c0 + n * 16;
      float bv = dob ? bias[c] : 0.f;
      if (vside) {
        const long rb = r0 + m * 16;
        short4v pv;
#pragma unroll
        for (int i = 0; i < 4; ++i) pv[i] = f2bf(acc[m][n][i] * alpha + bv);
        const long vr = ((rb >> 11) << 21) + ((c - 2048) << 11) + (rb & 2047);
        *(short4v*)&vTo[vr] = pv;
      } else {
#pragma unroll
        for (int i = 0; i < 4; ++i) {
          const long r = r0 + m * 16 + i;
          float v = acc[m][n][i] * alpha + bv;
          if (dor) v = fmaxf(v, 0.f);
          if (f32o) Cf[r * ldc + c] = v;
          else      Cb[r * ldc + c] = f2bf(v);
        }
      }
    }
}

// ---------------- gemmT8: 128x128, 3 blocks/CU (ctx, MLP) ----------------
__global__ __launch_bounds__(512, 6) void gemmT8(
    const short* __restrict__ A, const short* __restrict__ B,
    const float* __restrict__ bias, float alpha, void* __restrict__ Cout,
    int K, int lda, int ldb, int ldc,
    long sA, long sB, long sC, int flags)
{
  constexpr int BUFB = 16384;
  __shared__ __attribute__((aligned(16))) char lds[3 * BUFB];

  const int tid  = threadIdx.x;
  const int lane = tid & 63;
  const int wid  = tid >> 6;
  const int wm = wid >> 2, wn = wid & 3;   // 2(M) x 4(N); wave tile 64x32
  const int lr = lane & 15;
  const int kq = lane >> 4;

  const long m0 = (long)blockIdx.x * 128;
  const long n0 = (long)blockIdx.y * 128;
  const short* Ab = A + (long)blockIdx.z * sA;
  const short* Bb = B + (long)blockIdx.z * sB;

  const int sc8 = (((tid & 3) ^ ((tid >> 3) & 3)) << 3);
  const short* pA = Ab + (m0 + (tid >> 2)) * (long)lda + sc8;
  const short* pB = Bb + (n0 + (tid >> 2)) * (long)ldb + sc8;

  char* ldsB = lds;
  const int dst0 = tid * 16;

  auto stage = [&](int bs, int kt) {
    const long ko = (long)kt * 32;
    gload_lds16(pA + ko, ldsB + bs + dst0);
    gload_lds16(pB + ko, ldsB + bs + 8192 + dst0);
  };

  const int swz = ((kq ^ ((lr >> 1) & 3)) << 4);
  const int baseA = (wm * 64 + lr) * 64 + swz;
  const int baseB = 8192 + (wn * 32 + lr) * 64 + swz;

  float4v acc[4][2];
#pragma unroll
  for (int m = 0; m < 4; ++m)
#pragma unroll
    for (int n = 0; n < 2; ++n)
#pragma unroll
      for (int i = 0; i < 4; ++i) acc[m][n][i] = 0.f;

  const int NT = K >> 5;

  stage(0, 0);
  stage(BUFB, 1);
  asm volatile("s_waitcnt vmcnt(2)" ::: "memory");
  __builtin_amdgcn_s_barrier();
  CFENCE;

  int bsR = 0;
  int bsS = 2 * BUFB;

  for (int t = 0; t < NT; ++t) {
    if (t + 2 < NT) stage(bsS, t + 2);

    const char* rA = ldsB + (bsR + baseA);
    const char* rB = ldsB + (bsR + baseB);
    short8 a0 = *(const short8*)(rA);
    short8 a1 = *(const short8*)(rA + 1024);
    short8 a2 = *(const short8*)(rA + 2048);
    short8 a3 = *(const short8*)(rA + 3072);
    short8 b0 = *(const short8*)(rB);
    short8 b1 = *(const short8*)(rB + 1024);

    asm volatile("s_waitcnt lgkmcnt(0)" ::: "memory");
    SCHEDB;
    __builtin_amdgcn_s_setprio(1);
    acc[0][0] = MFMA16(a0, b0, acc[0][0], 0, 0, 0);
    acc[0][1] = MFMA16(a0, b1, acc[0][1], 0, 0, 0);
    acc[1][0] = MFMA16(a1, b0, acc[1][0], 0, 0, 0);
    acc[1][1] = MFMA16(a1, b1, acc[1][1], 0, 0, 0);
    acc[2][0] = MFMA16(a2, b0, acc[2][0], 0, 0, 0);
    acc[2][1] = MFMA16(a2, b1, acc[2][1], 0, 0, 0);
    acc[3][0] = MFMA16(a3, b0, acc[3][0], 0, 0, 0);
    acc[3][1] = MFMA16(a3, b1, acc[3][1], 0, 0, 0);
    __builtin_amdgcn_s_setprio(0);

    if (t + 2 < NT) { asm volatile("s_waitcnt vmcnt(2)" ::: "memory"); }
    else            { asm volatile("s_waitcnt vmcnt(0)" ::: "memory"); }
    __builtin_amdgcn_s_barrier();
    CFENCE;

    bsR = (bsR == 2 * BUFB) ? 0 : bsR + BUFB;
    bsS = (bsS == 2 * BUFB) ? 0 : bsS + BUFB;
  }

  const int dob = flags & 1, dor = flags & 2, f32o = flags & 4;
  float* Cf = (float*)Cout + (long)blockIdx.z * sC;
  short* Cb = (short*)Cout + (long)blockIdx.z * sC;
  const long r0 = m0 + wm * 64 + kq * 4;
  const long c0 = n0 + wn * 32 + lr;
#pragma unroll
  for (int m = 0; m < 4; ++m)
#pragma unroll
    for (int n = 0; n < 2; ++n) {
      const long c = c0 + n * 16;
      float bv = dob ? bias[c] : 0.f;
#pragma unroll
      for (int i = 0; i < 4; ++i) {
        const long r = r0 + m * 16 + i;
        float v = acc[m][n][i] * alpha + bv;
        if (dor) v = fmaxf(v, 0.f);
        if (f32o) Cf[r * ldc + c] = v;
        else      Cb[r * ldc + c] = f2bf(v);
      }
    }
}

// ---------------- elementwise / utility kernels ----------------

__global__ __launch_bounds__(256) void cast_x_k(const float* __restrict__ X,
                                                short* __restrict__ Xb) {
  int i = blockIdx.x * 256 + threadIdx.x;
  float4v v = ((const float4v*)X)[i];
  short4v o;
#pragma unroll
  for (int j = 0; j < 4; ++j) o[j] = f2bf(v[j]);
  ((short4v*)Xb)[i] = o;
}

__global__ __launch_bounds__(256) void wcast_k(
    const float* __restrict__ Wq, const float* __restrict__ Wk,
    const float* __restrict__ Wv, const float* __restrict__ W1,
    const float* __restrict__ W2, const float* __restrict__ W3,
    const float* __restrict__ bq, const float* __restrict__ bk,
    const float* __restrict__ bv,
    short* __restrict__ Wqkvt, short* __restrict__ W1t,
    short* __restrict__ W2t, short* __restrict__ W3t,
    float* __restrict__ bqkv) {
  const int z = blockIdx.z;
  if (z == 6) {
    if (blockIdx.y != 0 || blockIdx.x >= 12) return;
    int i = blockIdx.x * 256 + threadIdx.x;
    bqkv[i] = i < 1024 ? bq[i] : (i < 2048 ? bk[i - 1024] : bv[i - 2048]);
    return;
  }
  const float* W = z == 0 ? Wq : z == 1 ? Wk : z == 2 ? Wv : z == 3 ? W1 : z == 4 ? W2 : W3;
  short* Wt = z == 0 ? Wqkvt : z == 1 ? Wqkvt + 1048576 : z == 2 ? Wqkvt + 2097152
            : z == 3 ? W1t : z == 4 ? W2t : W3t;
  __shared__ float tile[32][33];
  int tx = threadIdx.x & 31, ty = threadIdx.x >> 5;
  int c0 = blockIdx.x * 32, r0 = blockIdx.y * 32;
#pragma unroll
  for (int r = ty; r < 32; r += 8)
    tile[r][tx] = W[(long)(r0 + r) * 1024 + c0 + tx];
  __syncthreads();
#pragma unroll
  for (int r = ty; r < 32; r += 8)
    Wt[(long)(c0 + r) * 1024 + r0 + tx] = f2bf(tile[tx][r]);
}

__global__ __launch_bounds__(256) void softmax_k(short* __restrict__ s) {
  __shared__ float red[8];
  long r = blockIdx.x;
  short* p = s + r * 2048;
  int tid = threadIdx.x;
  short8 raw = *(short8*)&p[tid * 8];
  float v[8];
  float mx = -1e30f;
#pragma unroll
  for (int j = 0; j < 8; ++j) { v[j] = bf2f(raw[j]); mx = fmaxf(mx, v[j]); }
#pragma unroll
  for (int o = 32; o; o >>= 1) mx = fmaxf(mx, __shfl_xor(mx, o));
  if ((tid & 63) == 0) red[tid >> 6] = mx;
  __syncthreads();
  mx = fmaxf(fmaxf(red[0], red[1]), fmaxf(red[2], red[3]));
  float sum = 0.f;
#pragma unroll
  for (int j = 0; j < 8; ++j) { v[j] = __expf(v[j] - mx); sum += v[j]; }
#pragma unroll
  for (int o = 32; o; o >>= 1) sum += __shfl_xor(sum, o);
  if ((tid & 63) == 0) red[4 + (tid >> 6)] = sum;
  __syncthreads();
  float inv = 1.f / (red[4] + red[5] + red[6] + red[7]);
  short8 o8;
#pragma unroll
  for (int j = 0; j < 8; ++j) o8[j] = f2bf(v[j] * inv);
  *(short8*)&p[tid * 8] = o8;
}

// LN(a_bf + b_bf): outf fp32 (optional), outb bf16 (optional)
__global__ __launch_bounds__(256) void addln2_k(const short* __restrict__ a,
                                                const short* __restrict__ b,
                                                const float* __restrict__ g,
                                                const float* __restrict__ be,
                                                float* __restrict__ outf,
                                                short* __restrict__ outb) {
  __shared__ float red[8];
  long r = blockIdx.x;
  int tid = threadIdx.x;
  short4v va = ((const short4v*)(a + r * 1024))[tid];
  short4v vb = ((const short4v*)(b + r * 1024))[tid];
  float x[4]; float s = 0.f;
#pragma unroll
  for (int j = 0; j < 4; ++j) { x[j] = bf2f(va[j]) + bf2f(vb[j]); s += x[j]; }
#pragma unroll
  for (int o = 32; o; o >>= 1) s += __shfl_xor(s, o);
  if ((tid & 63) == 0) red[tid >> 6] = s;
  __syncthreads();
  float mu = (red[0] + red[1] + red[2] + red[3]) * (1.f / 1024.f);
  float ss = 0.f;
#pragma unroll
  for (int j = 0; j < 4; ++j) { float d = x[j] - mu; ss += d * d; }
#pragma unroll
  for (int o = 32; o; o >>= 1) ss += __shfl_xor(ss, o);
  if ((tid & 63) == 0) red[4 + (tid >> 6)] = ss;
  __syncthreads();
  float var = (red[4] + red[5] + red[6] + red[7]) * (1.f / 1024.f);
  float rstd = rsqrtf(var + 1e-5f);
  float4v vg = ((const float4v*)g)[tid];
  float4v vbe = ((const float4v*)be)[tid];
  float4v y;
#pragma unroll
  for (int j = 0; j < 4; ++j) y[j] = (x[j] - mu) * rstd * vg[j] + vbe[j];
  if (outf) ((float4v*)(outf + r * 1024))[tid] = y;
  if (outb) {
    short4v ob;
#pragma unroll
    for (int j = 0; j < 4; ++j) ob[j] = f2bf(y[j]);
    ((short4v*)(outb + r * 1024))[tid] = ob;
  }
}

// ---------------- host launcher ----------------

extern "C" void kernel_launch(void* const* d_in, const int* in_sizes, int n_in,
                              void* d_out, int out_size, void* d_ws, size_t ws_size,
                              hipStream_t stream) {
  const float* X  = (const float*)d_in[0];
  const float* Wq = (const float*)d_in[1];
  const float* bq = (const float*)d_in[2];
  const float* Wk = (const float*)d_in[3];
  const float* bk = (const float*)d_in[4];
  const float* Wv = (const float*)d_in[5];
  const float* bv = (const float*)d_in[6];
  const float* W1 = (const float*)d_in[7];
  const float* b1 = (const float*)d_in[8];
  const float* W2 = (const float*)d_in[9];
  const float* b2 = (const float*)d_in[10];
  const float* W3 = (const float*)d_in[11];
  const float* b3 = (const float*)d_in[12];
  const float* g1  = (const float*)d_in[13];
  const float* be1 = (const float*)d_in[14];
  const float* g2  = (const float*)d_in[15];
  const float* be2 = (const float*)d_in[16];

  char* ws = (char*)d_ws;
  short* Xb     = (short*)(ws + 0);           // 16.7 MB, live to LN1
  short* Wqkvt  = (short*)(ws + 16777216);
  short* W1t    = (short*)(ws + 23068672);
  short* W2t    = (short*)(ws + 25165824);
  short* W3t    = (short*)(ws + 27262976);
  float* bqkv   = (float*)(ws + 29360128);
  short* qk     = (short*)(ws + 29372416);    // [8192][2048] bf16 = 33.5 MB
  short* vT     = (short*)(ws + 62926848);    // [4][1024][2048] bf16 = 16.7 MB
  short* scores = (short*)(ws + 79704064);    // 33.5 MB
  short* ctx    = (short*)(ws + 29372416);    // over qk lower half
  short* hbuf   = (short*)(ws + 46149632);    // over qk upper half
  short* m1     = (short*)(ws + 62926848);    // over vT (dead after ctx)
  short* m2     = (short*)(ws + 79704064);    // over scores (dead after ctx)
  short* m3     = (short*)(ws + 96481280);
  float* out    = (float*)d_out;

  cast_x_k<<<8192, 256, 0, stream>>>(X, Xb);
  wcast_k<<<dim3(32, 32, 7), 256, 0, stream>>>(Wq, Wk, Wv, W1, W2, W3,
                                               bq, bk, bv,
                                               Wqkvt, W1t, W2t, W3t, bqkv);

  // QKV: q,k -> qk [8192][2048]; v -> vT transposed. grid 32x24
  gemmT4<<<dim3(32, 24, 1), 512, 0, stream>>>(
      Xb, Wqkvt, bqkv, 1.0f, qk, 1024, 1024, 1024, 2048, 0, 0, 0, 1 | 8, vT);

  // scores[b] = q k^T / 32; grid 8x16x4 (512 blocks, 2/CU)
  gemmT4<<<dim3(8, 16, 4), 512, 0, stream>>>(
      qk, qk + 1024, nullptr, 0.03125f, scores, 1024, 2048, 2048, 2048,
      (long)2048 * 2048, (long)2048 * 2048, (long)2048 * 2048, 0, nullptr);

  softmax_k<<<8192, 256, 0, stream>>>(scores);

  // ctx[b] = attn @ v (bf16); gemmT8 grid 16x8x4 = 512 blocks
  gemmT8<<<dim3(16, 8, 4), 512, 0, stream>>>(
      scores, vT, nullptr, 1.0f, ctx, 2048, 2048, 2048, 1024,
      (long)2048 * 2048, (long)1024 * 2048, (long)2048 * 1024, 0);

  // h = LN(ctx + Xb), bf16 only
  addln2_k<<<8192, 256, 0, stream>>>(ctx, Xb, g1, be1, nullptr, hbuf);

  // MLP: gemmT8 grid 64x8 = 512 blocks each; bf16 outputs
  gemmT8<<<dim3(64, 8, 1), 512, 0, stream>>>(
      hbuf, W1t, b1, 1.0f, m1, 1024, 1024, 1024, 1024, 0, 0, 0, 3);
  gemmT8<<<dim3(64, 8, 1), 512, 0, stream>>>(
      m1, W2t, b2, 1.0f, m2, 1024, 1024, 1024, 1024, 0, 0, 0, 3);
  gemmT8<<<dim3(64, 8, 1), 512, 0, stream>>>(
      m2, W3t, b3, 1.0f, m3, 1024, 1024, 1024, 1024, 0, 0, 0, 1);

  // out = LN(m3 + h), fp32
  addln2_k<<<8192, 256, 0, stream>>>(m3, hbuf, g2, be2, out, nullptr);
}